// Round 4
// baseline (718.669 us; speedup 1.0000x reference)
//
#include <hip/hip_runtime.h>
#include <stdint.h>

#define BB 16
#define NN 4096
#define DD 128
#define MM 1024
#define RADIUS2 0.04f
#define TPB 256
#define PPT 16             // points per thread: 256*16 = 4096
#define NPAIR (PPT / 2)
#define NW  (TPB / 64)     // 4 waves, 1 per SIMD

typedef unsigned long long u64;
typedef unsigned int u32;
typedef float f32x2 __attribute__((ext_vector_type(2)));
typedef unsigned int uint2v __attribute__((ext_vector_type(2)));

__device__ __forceinline__ u32 umin2(u32 a, u32 b) { return a < b ? a : b; }
__device__ __forceinline__ u32 umin3(u32 a, u32 b, u32 c) { return umin2(umin2(a, b), c); }  // v_min3_u32
__device__ __forceinline__ float fmax3(float a, float b, float c) { return fmaxf(fmaxf(a, b), c); } // v_max3_f32

template <int CTRL>
__device__ __forceinline__ float dpp_fmax(float v) {
    int o = __builtin_amdgcn_update_dpp(0, __float_as_int(v), CTRL, 0xF, 0xF, true);
    return fmaxf(v, __int_as_float(o));
}
template <int CTRL>
__device__ __forceinline__ u32 dpp_umin(u32 v) {
    u32 o = (u32)__builtin_amdgcn_update_dpp(0, (int)v, CTRL, 0xF, 0xF, true);
    return umin2(v, o);
}

// xor-16 combine: permlane16_swap at VALU speed (ds_swizzle fallback, verified r2/r3)
__device__ __forceinline__ float xor16_fmax(float v) {
#if __has_builtin(__builtin_amdgcn_permlane16_swap)
    uint2v r = __builtin_amdgcn_permlane16_swap(__float_as_uint(v), __float_as_uint(v), false, false);
    return fmaxf(__uint_as_float(r[0]), __uint_as_float(r[1]));
#else
    int o = __builtin_amdgcn_ds_swizzle(__float_as_int(v), 0x401F);
    return fmaxf(v, __int_as_float(o));
#endif
}
__device__ __forceinline__ u32 xor16_umin(u32 v) {
#if __has_builtin(__builtin_amdgcn_permlane16_swap)
    uint2v r = __builtin_amdgcn_permlane16_swap(v, v, false, false);
    return umin2(r[0], r[1]);
#else
    u32 o = (u32)__builtin_amdgcn_ds_swizzle((int)v, 0x401F);
    return umin2(v, o);
#endif
}
__device__ __forceinline__ float xor32_fmax(float v) {
#if __has_builtin(__builtin_amdgcn_permlane32_swap)
    uint2v r = __builtin_amdgcn_permlane32_swap(__float_as_uint(v), __float_as_uint(v), false, false);
    return fmaxf(__uint_as_float(r[0]), __uint_as_float(r[1]));
#else
    return fmaxf(v, __shfl_xor(v, 32, 64));
#endif
}
__device__ __forceinline__ u32 xor32_umin(u32 v) {
#if __has_builtin(__builtin_amdgcn_permlane32_swap)
    uint2v r = __builtin_amdgcn_permlane32_swap(v, v, false, false);
    return umin2(r[0], r[1]);
#else
    return umin2(v, __shfl_xor(v, 32, 64));
#endif
}

__device__ __forceinline__ float wave_fmax(float v) {
    v = dpp_fmax<0xB1>(v);     // quad_perm xor1
    v = dpp_fmax<0x4E>(v);     // quad_perm xor2
    v = dpp_fmax<0x141>(v);    // row_half_mirror
    v = dpp_fmax<0x140>(v);    // row_mirror
    v = xor16_fmax(v);
    v = xor32_fmax(v);
    return v;
}
__device__ __forceinline__ u32 wave_umin(u32 v) {
    v = dpp_umin<0xB1>(v);
    v = dpp_umin<0x4E>(v);
    v = dpp_umin<0x141>(v);
    v = dpp_umin<0x140>(v);
    v = xor16_umin(v);
    v = xor32_umin(v);
    return v;
}

// ---------------------------------------------------------------------------
// FPS: one block (4 waves) per graph. Per iteration:
//   - packed f32x2 dist update (bit-exact, contraction off)
//   - thread argmax-local scan vs OWN tmax (off critical path)
//   - speculative pos4[cand_local] read (overlaps both wave reduces)
//   - wave fmax -> 1 select -> wave umin (DPP + permlane, no DS pipe)
//   - unique winner lane writes {wmax, x, y, z} + idx -> 1 barrier -> fold:
//     next coords available to ALL lanes without a dependent pos4[last] read.
// Tie-break = lowest global index everywhere (waves/lanes own ascending
// contiguous ranges; umin/min3 within; descending wave fold across).
// ---------------------------------------------------------------------------
__global__ __launch_bounds__(TPB) void fps_kernel(const float* __restrict__ pos,
                                                  int* __restrict__ idx_out) {
    const int b   = blockIdx.x;
    const int tid = threadIdx.x;
    const int wid = tid >> 6;

    __shared__ float4 pos4[NN];        // xyz_ padded, b128 reads
    __shared__ float4 fpart[2][NW];    // {wmax, cx, cy, cz}, double-buffered
    __shared__ u32    ipart[2][NW];

    const float* pg = pos + (size_t)b * NN * 3;
    for (int k = tid; k < NN * 3; k += TPB)
        ((float*)&pos4[k / 3])[k % 3] = pg[k];
    __syncthreads();

    f32x2 px[NPAIR], py[NPAIR], pz[NPAIR], dist2[NPAIR];
#pragma unroll
    for (int j = 0; j < NPAIR; ++j) {
        float4 a = pos4[tid * PPT + 2 * j];
        float4 c = pos4[tid * PPT + 2 * j + 1];
        px[j] = (f32x2){a.x, c.x};
        py[j] = (f32x2){a.y, c.y};
        pz[j] = (f32x2){a.z, c.z};
        dist2[j] = (f32x2){__builtin_inff(), __builtin_inff()};
    }

    if (tid == 0) idx_out[b * MM] = 0;     // idx[0] = 0 (scan records before update)
    float4 lp = pos4[0];
    float lx = lp.x, ly = lp.y, lz = lp.z;

    for (int m = 1; m < MM; ++m) {
        // ---- distance update: packed pairs, separate roundings, no FMA
        {
#pragma clang fp contract(off)
            f32x2 vx = {lx, lx}, vy = {ly, ly}, vz = {lz, lz};
#pragma unroll
            for (int j = 0; j < NPAIR; ++j) {
                f32x2 dx = px[j] - vx;
                f32x2 dy = py[j] - vy;
                f32x2 dz = pz[j] - vz;
                f32x2 d  = dx * dx + dy * dy;
                d = d + dz * dz;
                dist2[j] = __builtin_elementwise_min(dist2[j], d);
            }
        }

        // ---- thread max of 16 (max3 tree)
        float t0 = fmaxf(dist2[0].x, dist2[0].y);
        float t1 = fmaxf(dist2[1].x, dist2[1].y);
        float t2 = fmaxf(dist2[2].x, dist2[2].y);
        float t3 = fmaxf(dist2[3].x, dist2[3].y);
        float t4 = fmaxf(dist2[4].x, dist2[4].y);
        float t5 = fmaxf(dist2[5].x, dist2[5].y);
        float t6 = fmaxf(dist2[6].x, dist2[6].y);
        float t7 = fmaxf(dist2[7].x, dist2[7].y);
        float tmax = fmax3(fmax3(t0, t1, t2), fmax3(t3, t4, t5), fmaxf(t6, t7));

        // ---- local scan vs tmax (lowest k), sentinel 64 = inline const
        u32 c[PPT];
#pragma unroll
        for (int j = 0; j < NPAIR; ++j) {
            c[2 * j]     = (dist2[j].x == tmax) ? (u32)(2 * j)     : 64u;
            c[2 * j + 1] = (dist2[j].y == tmax) ? (u32)(2 * j + 1) : 64u;
        }
        u32 a0 = umin3(c[0],  c[1],  c[2]);
        u32 a1 = umin3(c[3],  c[4],  c[5]);
        u32 a2 = umin3(c[6],  c[7],  c[8]);
        u32 a3 = umin3(c[9],  c[10], c[11]);
        u32 a4 = umin3(c[12], c[13], c[14]);
        u32 sl = umin3(umin3(a0, a1, a2), umin2(a3, a4), c[15]);
        u32 gidx = (u32)(tid * PPT) + sl;

        float4 sp = pos4[gidx];            // speculative winner coords (hidden under reduces)

        float wmax = wave_fmax(tmax);
        u32 cand = (tmax == wmax) ? gidx : 0xFFFFFFFFu;
        u32 widx = wave_umin(cand);

        const int buf = m & 1;
        if (cand == widx) {                // exactly one lane per wave
            fpart[buf][wid] = make_float4(wmax, sp.x, sp.y, sp.z);
            ipart[buf][wid] = widx;
        }
        __syncthreads();

        float4 q0 = fpart[buf][0];
        float4 q1 = fpart[buf][1];
        float4 q2 = fpart[buf][2];
        float4 q3 = fpart[buf][3];
        float g = fmaxf(fmaxf(q0.x, q1.x), fmaxf(q2.x, q3.x));
        // descending selects: wave 0 wins ties (lowest index range)
        float nx = q3.y, ny = q3.z, nz = q3.w;
        bool b2 = (q2.x == g); nx = b2 ? q2.y : nx; ny = b2 ? q2.z : ny; nz = b2 ? q2.w : nz;
        bool b1 = (q1.x == g); nx = b1 ? q1.y : nx; ny = b1 ? q1.z : ny; nz = b1 ? q1.w : nz;
        bool b0 = (q0.x == g); nx = b0 ? q0.y : nx; ny = b0 ? q0.z : ny; nz = b0 ? q0.w : nz;
        lx = nx; ly = ny; lz = nz;

        if (tid == 0) {                    // index only needed for output
            u32 li = ipart[buf][3];
            li = b2 ? ipart[buf][2] : li;
            li = b1 ? ipart[buf][1] : li;
            li = b0 ? ipart[buf][0] : li;
            idx_out[b * MM + m] = (int)li;
        }
    }
}

// ---------------------------------------------------------------------------
// Phase 2a: gather sampled_x (float4-vectorized).
// ---------------------------------------------------------------------------
__global__ void gather_x_kernel(const float* __restrict__ x,
                                const int* __restrict__ idx,
                                float* __restrict__ out) {
    int t = blockIdx.x * blockDim.x + threadIdx.x;
    if (t >= BB * MM * DD / 4) return;
    int row = t >> 5;               // DD/4 = 32 float4 per row
    int c4  = (t & 31) << 2;
    int b   = row >> 10;
    int n   = idx[row];
    const float4 v = *(const float4*)(x + ((size_t)(b * NN + n) * DD + c4));
    *(float4*)(out + (size_t)row * DD + c4) = v;
}

// ---------------------------------------------------------------------------
// Phase 2b: gather sampled_pos + batch ids (as float).
// ---------------------------------------------------------------------------
__global__ void gather_pb_kernel(const float* __restrict__ pos,
                                 const int* __restrict__ idx,
                                 float* __restrict__ spos,
                                 float* __restrict__ sbatch) {
    int r = blockIdx.x * blockDim.x + threadIdx.x;
    if (r >= BB * MM) return;
    int b = r >> 10;
    int n = idx[r];
    const float* p = pos + (size_t)(b * NN + n) * 3;
    spos[r * 3 + 0] = p[0];
    spos[r * 3 + 1] = p[1];
    spos[r * 3 + 2] = p[2];
    sbatch[r] = (float)b;
}

// ---------------------------------------------------------------------------
// Phase 3: radius adjacency, bit-exact d2 (no FMA).
// ---------------------------------------------------------------------------
__global__ void adj_kernel(const float* __restrict__ spos,
                           float* __restrict__ adj) {
    int row = blockIdx.x;           // b*MM + i
    int b   = row >> 10;
    int i   = row & (MM - 1);
    const float* pb = spos + (size_t)b * MM * 3;
    float xi = pb[i * 3 + 0];
    float yi = pb[i * 3 + 1];
    float zi = pb[i * 3 + 2];

    int j0 = threadIdx.x << 2;
    float4 r;
    float* o = adj + (size_t)row * MM;
#pragma unroll
    for (int k = 0; k < 4; ++k) {
        int j = j0 + k;
        float dx = xi - pb[j * 3 + 0];
        float dy = yi - pb[j * 3 + 1];
        float dz = zi - pb[j * 3 + 2];
        float d2 = __fadd_rn(__fadd_rn(__fmul_rn(dx, dx), __fmul_rn(dy, dy)),
                             __fmul_rn(dz, dz));
        float v = (d2 <= RADIUS2 && j != i) ? 1.0f : 0.0f;
        ((float*)&r)[k] = v;
    }
    *(float4*)(o + j0) = r;
}

// ---------------------------------------------------------------------------
extern "C" void kernel_launch(void* const* d_in, const int* in_sizes, int n_in,
                              void* d_out, int out_size, void* d_ws, size_t ws_size,
                              hipStream_t stream) {
    const float* x   = (const float*)d_in[0];
    const float* pos = (const float*)d_in[1];

    float* out    = (float*)d_out;
    int*   idx_ws = (int*)d_ws;                 // BB*MM ints = 64 KB scratch

    float* sx   = out;                          // [BB*MM, DD]
    float* spos = sx + (size_t)BB * MM * DD;    // [BB*MM, 3]
    float* sbat = spos + (size_t)BB * MM * 3;   // [BB*MM]
    float* adj  = sbat + (size_t)BB * MM;       // [BB, MM, MM]

    fps_kernel<<<BB, TPB, 0, stream>>>(pos, idx_ws);
    gather_x_kernel<<<(BB * MM * DD / 4 + 255) / 256, 256, 0, stream>>>(x, idx_ws, sx);
    gather_pb_kernel<<<(BB * MM + 255) / 256, 256, 0, stream>>>(pos, idx_ws, spos, sbat);
    adj_kernel<<<BB * MM, 256, 0, stream>>>(spos, adj);
}

// Round 5
// 707.135 us; speedup vs baseline: 1.0163x; 1.0163x over previous
//
#include <hip/hip_runtime.h>
#include <stdint.h>

#define BB 16
#define NN 4096
#define DD 128
#define MM 1024
#define RADIUS2 0.04f
#define TPB 256
#define PPT 16             // points per thread: 256*16 = 4096
#define NPAIR (PPT / 2)
#define NW  (TPB / 64)     // 4 waves, 1 per SIMD

typedef unsigned long long u64;
typedef unsigned int u32;
typedef float f32x2 __attribute__((ext_vector_type(2)));
typedef unsigned int uint2v __attribute__((ext_vector_type(2)));

__device__ __forceinline__ u32 umin2(u32 a, u32 b) { return a < b ? a : b; }
__device__ __forceinline__ u32 umin3(u32 a, u32 b, u32 c) { return umin2(umin2(a, b), c); }  // v_min3_u32
__device__ __forceinline__ float fmax3(float a, float b, float c) { return fmaxf(fmaxf(a, b), c); } // v_max3_f32

template <int CTRL>
__device__ __forceinline__ float dpp_fmax(float v) {
    int o = __builtin_amdgcn_update_dpp(0, __float_as_int(v), CTRL, 0xF, 0xF, true);
    return fmaxf(v, __int_as_float(o));
}
template <int CTRL>
__device__ __forceinline__ u32 dpp_umin(u32 v) {
    u32 o = (u32)__builtin_amdgcn_update_dpp(0, (int)v, CTRL, 0xF, 0xF, true);
    return umin2(v, o);
}

// xor-16 combine: permlane16_swap at VALU speed (ds_swizzle fallback)
__device__ __forceinline__ float xor16_fmax(float v) {
#if __has_builtin(__builtin_amdgcn_permlane16_swap)
    uint2v r = __builtin_amdgcn_permlane16_swap(__float_as_uint(v), __float_as_uint(v), false, false);
    return fmaxf(__uint_as_float(r[0]), __uint_as_float(r[1]));
#else
    int o = __builtin_amdgcn_ds_swizzle(__float_as_int(v), 0x401F);
    return fmaxf(v, __int_as_float(o));
#endif
}
__device__ __forceinline__ u32 xor16_umin(u32 v) {
#if __has_builtin(__builtin_amdgcn_permlane16_swap)
    uint2v r = __builtin_amdgcn_permlane16_swap(v, v, false, false);
    return umin2(r[0], r[1]);
#else
    u32 o = (u32)__builtin_amdgcn_ds_swizzle((int)v, 0x401F);
    return umin2(v, o);
#endif
}
__device__ __forceinline__ float xor32_fmax(float v) {
#if __has_builtin(__builtin_amdgcn_permlane32_swap)
    uint2v r = __builtin_amdgcn_permlane32_swap(__float_as_uint(v), __float_as_uint(v), false, false);
    return fmaxf(__uint_as_float(r[0]), __uint_as_float(r[1]));
#else
    return fmaxf(v, __shfl_xor(v, 32, 64));
#endif
}
__device__ __forceinline__ u32 xor32_umin(u32 v) {
#if __has_builtin(__builtin_amdgcn_permlane32_swap)
    uint2v r = __builtin_amdgcn_permlane32_swap(v, v, false, false);
    return umin2(r[0], r[1]);
#else
    return umin2(v, __shfl_xor(v, 32, 64));
#endif
}

__device__ __forceinline__ float wave_fmax(float v) {
    v = dpp_fmax<0xB1>(v);     // quad_perm xor1
    v = dpp_fmax<0x4E>(v);     // quad_perm xor2
    v = dpp_fmax<0x141>(v);    // row_half_mirror
    v = dpp_fmax<0x140>(v);    // row_mirror
    v = xor16_fmax(v);
    v = xor32_fmax(v);
    return v;
}
__device__ __forceinline__ u32 wave_umin(u32 v) {
    v = dpp_umin<0xB1>(v);
    v = dpp_umin<0x4E>(v);
    v = dpp_umin<0x141>(v);
    v = dpp_umin<0x140>(v);
    v = xor16_umin(v);
    v = xor32_umin(v);
    return v;
}

// ---------------------------------------------------------------------------
// FPS: one block (4 waves) per graph. KEY CHANGE vs r4: NO global stores inside
// the loop — winner indices go to an LDS trace[] and are dumped after the loop.
// This removes the s_waitcnt vmcnt(0) drain that __syncthreads forces before
// s_barrier (the ~800cy/iter sticky stall across r1-r4).
// ---------------------------------------------------------------------------
__global__ __launch_bounds__(TPB) void fps_kernel(const float* __restrict__ pos,
                                                  int* __restrict__ idx_out) {
    const int b   = blockIdx.x;
    const int tid = threadIdx.x;
    const int wid = tid >> 6;

    __shared__ float4 pos4[NN];        // xyz_ padded, b128 reads
    __shared__ float4 fpart[2][NW];    // {wmax, cx, cy, cz}, double-buffered
    __shared__ u32    ipart[2][NW];
    __shared__ int    trace[MM];       // selected indices (dumped post-loop)

    const float* pg = pos + (size_t)b * NN * 3;
    for (int k = tid; k < NN * 3; k += TPB)
        ((float*)&pos4[k / 3])[k % 3] = pg[k];
    if (tid == 0) trace[0] = 0;        // idx[0] = 0 (scan records before update)
    __syncthreads();

    f32x2 px[NPAIR], py[NPAIR], pz[NPAIR], dist2[NPAIR];
#pragma unroll
    for (int j = 0; j < NPAIR; ++j) {
        float4 a = pos4[tid * PPT + 2 * j];
        float4 c = pos4[tid * PPT + 2 * j + 1];
        px[j] = (f32x2){a.x, c.x};
        py[j] = (f32x2){a.y, c.y};
        pz[j] = (f32x2){a.z, c.z};
        dist2[j] = (f32x2){__builtin_inff(), __builtin_inff()};
    }

    float4 lp = pos4[0];
    float lx = lp.x, ly = lp.y, lz = lp.z;

    for (int m = 1; m < MM; ++m) {
        // ---- distance update: packed pairs, separate roundings, no FMA
        {
#pragma clang fp contract(off)
            f32x2 vx = {lx, lx}, vy = {ly, ly}, vz = {lz, lz};
#pragma unroll
            for (int j = 0; j < NPAIR; ++j) {
                f32x2 dx = px[j] - vx;
                f32x2 dy = py[j] - vy;
                f32x2 dz = pz[j] - vz;
                f32x2 d  = dx * dx + dy * dy;
                d = d + dz * dz;
                dist2[j] = __builtin_elementwise_min(dist2[j], d);
            }
        }

        // ---- thread max of 16 (max3 tree)
        float t0 = fmaxf(dist2[0].x, dist2[0].y);
        float t1 = fmaxf(dist2[1].x, dist2[1].y);
        float t2 = fmaxf(dist2[2].x, dist2[2].y);
        float t3 = fmaxf(dist2[3].x, dist2[3].y);
        float t4 = fmaxf(dist2[4].x, dist2[4].y);
        float t5 = fmaxf(dist2[5].x, dist2[5].y);
        float t6 = fmaxf(dist2[6].x, dist2[6].y);
        float t7 = fmaxf(dist2[7].x, dist2[7].y);
        float tmax = fmax3(fmax3(t0, t1, t2), fmax3(t3, t4, t5), fmaxf(t6, t7));

        // ---- local scan vs tmax (lowest k), sentinel 64 = inline const
        u32 c[PPT];
#pragma unroll
        for (int j = 0; j < NPAIR; ++j) {
            c[2 * j]     = (dist2[j].x == tmax) ? (u32)(2 * j)     : 64u;
            c[2 * j + 1] = (dist2[j].y == tmax) ? (u32)(2 * j + 1) : 64u;
        }
        u32 a0 = umin3(c[0],  c[1],  c[2]);
        u32 a1 = umin3(c[3],  c[4],  c[5]);
        u32 a2 = umin3(c[6],  c[7],  c[8]);
        u32 a3 = umin3(c[9],  c[10], c[11]);
        u32 a4 = umin3(c[12], c[13], c[14]);
        u32 sl = umin3(umin3(a0, a1, a2), umin2(a3, a4), c[15]);
        u32 gidx = (u32)(tid * PPT) + sl;

        float4 sp = pos4[gidx];            // speculative winner coords (hidden under reduces)

        float wmax = wave_fmax(tmax);
        u32 cand = (tmax == wmax) ? gidx : 0xFFFFFFFFu;
        u32 widx = wave_umin(cand);

        const int buf = m & 1;
        if (cand == widx) {                // exactly one lane per wave
            fpart[buf][wid] = make_float4(wmax, sp.x, sp.y, sp.z);
            ipart[buf][wid] = widx;
        }
        __syncthreads();

        float4 q0 = fpart[buf][0];
        float4 q1 = fpart[buf][1];
        float4 q2 = fpart[buf][2];
        float4 q3 = fpart[buf][3];
        float g = fmaxf(fmaxf(q0.x, q1.x), fmaxf(q2.x, q3.x));
        // descending selects: wave 0 wins ties (lowest index range)
        float nx = q3.y, ny = q3.z, nz = q3.w;
        bool b2 = (q2.x == g); nx = b2 ? q2.y : nx; ny = b2 ? q2.z : ny; nz = b2 ? q2.w : nz;
        bool b1 = (q1.x == g); nx = b1 ? q1.y : nx; ny = b1 ? q1.z : ny; nz = b1 ? q1.w : nz;
        bool b0 = (q0.x == g); nx = b0 ? q0.y : nx; ny = b0 ? q0.z : ny; nz = b0 ? q0.w : nz;
        lx = nx; ly = ny; lz = nz;

        if (tid == 0) {                    // LDS trace, NOT global (no vmcnt drain)
            u32 li = ipart[buf][3];
            li = b2 ? ipart[buf][2] : li;
            li = b1 ? ipart[buf][1] : li;
            li = b0 ? ipart[buf][0] : li;
            trace[m] = (int)li;
        }
    }

    __syncthreads();                       // make last trace writes visible
    for (int k = tid; k < MM; k += TPB)    // batched dump: 4 stores/thread
        idx_out[b * MM + k] = trace[k];
}

// ---------------------------------------------------------------------------
// Phase 2a: gather sampled_x (float4-vectorized).
// ---------------------------------------------------------------------------
__global__ void gather_x_kernel(const float* __restrict__ x,
                                const int* __restrict__ idx,
                                float* __restrict__ out) {
    int t = blockIdx.x * blockDim.x + threadIdx.x;
    if (t >= BB * MM * DD / 4) return;
    int row = t >> 5;               // DD/4 = 32 float4 per row
    int c4  = (t & 31) << 2;
    int b   = row >> 10;
    int n   = idx[row];
    const float4 v = *(const float4*)(x + ((size_t)(b * NN + n) * DD + c4));
    *(float4*)(out + (size_t)row * DD + c4) = v;
}

// ---------------------------------------------------------------------------
// Phase 2b: gather sampled_pos + batch ids (as float).
// ---------------------------------------------------------------------------
__global__ void gather_pb_kernel(const float* __restrict__ pos,
                                 const int* __restrict__ idx,
                                 float* __restrict__ spos,
                                 float* __restrict__ sbatch) {
    int r = blockIdx.x * blockDim.x + threadIdx.x;
    if (r >= BB * MM) return;
    int b = r >> 10;
    int n = idx[r];
    const float* p = pos + (size_t)(b * NN + n) * 3;
    spos[r * 3 + 0] = p[0];
    spos[r * 3 + 1] = p[1];
    spos[r * 3 + 2] = p[2];
    sbatch[r] = (float)b;
}

// ---------------------------------------------------------------------------
// Phase 3: radius adjacency, bit-exact d2 (no FMA).
// ---------------------------------------------------------------------------
__global__ void adj_kernel(const float* __restrict__ spos,
                           float* __restrict__ adj) {
    int row = blockIdx.x;           // b*MM + i
    int b   = row >> 10;
    int i   = row & (MM - 1);
    const float* pb = spos + (size_t)b * MM * 3;
    float xi = pb[i * 3 + 0];
    float yi = pb[i * 3 + 1];
    float zi = pb[i * 3 + 2];

    int j0 = threadIdx.x << 2;
    float4 r;
    float* o = adj + (size_t)row * MM;
#pragma unroll
    for (int k = 0; k < 4; ++k) {
        int j = j0 + k;
        float dx = xi - pb[j * 3 + 0];
        float dy = yi - pb[j * 3 + 1];
        float dz = zi - pb[j * 3 + 2];
        float d2 = __fadd_rn(__fadd_rn(__fmul_rn(dx, dx), __fmul_rn(dy, dy)),
                             __fmul_rn(dz, dz));
        float v = (d2 <= RADIUS2 && j != i) ? 1.0f : 0.0f;
        ((float*)&r)[k] = v;
    }
    *(float4*)(o + j0) = r;
}

// ---------------------------------------------------------------------------
extern "C" void kernel_launch(void* const* d_in, const int* in_sizes, int n_in,
                              void* d_out, int out_size, void* d_ws, size_t ws_size,
                              hipStream_t stream) {
    const float* x   = (const float*)d_in[0];
    const float* pos = (const float*)d_in[1];

    float* out    = (float*)d_out;
    int*   idx_ws = (int*)d_ws;                 // BB*MM ints = 64 KB scratch

    float* sx   = out;                          // [BB*MM, DD]
    float* spos = sx + (size_t)BB * MM * DD;    // [BB*MM, 3]
    float* sbat = spos + (size_t)BB * MM * 3;   // [BB*MM]
    float* adj  = sbat + (size_t)BB * MM;       // [BB, MM, MM]

    fps_kernel<<<BB, TPB, 0, stream>>>(pos, idx_ws);
    gather_x_kernel<<<(BB * MM * DD / 4 + 255) / 256, 256, 0, stream>>>(x, idx_ws, sx);
    gather_pb_kernel<<<(BB * MM + 255) / 256, 256, 0, stream>>>(pos, idx_ws, spos, sbat);
    adj_kernel<<<BB * MM, 256, 0, stream>>>(spos, adj);
}